// Round 21
// baseline (153.679 us; speedup 1.0000x reference)
//
#include <hip/hip_runtime.h>

typedef unsigned int u32;
typedef unsigned short u16;
typedef _Float16 f16x2 __attribute__((ext_vector_type(2)));
typedef _Float16 f16x8 __attribute__((ext_vector_type(8)));
typedef __bf16 bf16x8 __attribute__((ext_vector_type(8)));
typedef float f32x4 __attribute__((ext_vector_type(4)));

static __device__ __forceinline__ f16x2 bch(u32 u) { return __builtin_bit_cast(f16x2, u); }

// ---------------- ws layout (bytes) ----------------
// xq   (u32)  @ 0         : f16x2 pixel-major, [lvl][tb 4][g 4][hw][32 words]
// A    (u16)  @ 11141120  : bf16 weights [lvl][o 256][k 2304], k=(g*9+p)*64+c
// corr (f32)  @ 15859712  : [lvl][b][K2][HW]; dead after offset -> small-mode B buffer
// offs (f32)  @ 27875840  : [lvl][b][72][HW], 783360 floats (zero during corr = OOB scratch)
// part (f32)  @ 31009280  : 6 x 783360 partials (18.8 MB); dead after reduce ->
// big-mode B buffer @ 31009280: 10880 rows x 2304 bf16 (needs ws >= 81,144,320)

// ---------------- merged preamble: zero offs + pack + aconv(transposed) + out-copy(f4) ---
__global__ __launch_bounds__(256) void prep_kernel(
    const float* __restrict__ x0, const float* __restrict__ x1,
    const float* __restrict__ x2, const float* __restrict__ x3,
    const float* __restrict__ w0, const float* __restrict__ w1,
    const float* __restrict__ w2, const float* __restrict__ w3,
    u32* __restrict__ xq, u16* __restrict__ A, float* __restrict__ offs,
    float* __restrict__ out)
{
  __shared__ u32 plds[32 * 65];
  int bx = blockIdx.x, t = threadIdx.x;
  if (bx < 3060) {
    int i = bx * 256 + t;
    if (i < 783360) offs[i] = 0.f;
    return;
  }
  if (bx < 4420) {
    int local = bx - 3060;
    const float* xs; int lvlb, lgW, lgnch;
    if (local < 1024)      { xs = x0; lvlb = 0;       lgW = 6; lgnch = 6; }
    else if (local < 1280) { xs = x1; lvlb = 2097152; lgW = 5; lgnch = 4; local -= 1024; }
    else if (local < 1344) { xs = x2; lvlb = 2621440; lgW = 4; lgnch = 2; local -= 1280; }
    else                   { xs = x3; lvlb = 2752512; lgW = 3; lgnch = 0; local -= 1344; }
    int HW = 1 << (2 * lgW);
    int hc = local & ((1 << lgnch) - 1);
    int g  = (local >> lgnch) & 3;
    int tb = local >> (lgnch + 2);
    int hw0 = hc * 64;
    int lane = t & 63, qd = t >> 6;
#pragma unroll
    for (int j = 0; j < 8; ++j) {
      int cpw = qd * 8 + j;
      int c = tb * 256 + g * 64 + cpw * 2;
      const float* s = xs + (size_t)c * HW + hw0 + lane;
      float f0 = s[0], f1 = s[HW];
      f16x2 h; h[0] = (_Float16)f0; h[1] = (_Float16)f1;
      plds[cpw * 65 + lane] = __builtin_bit_cast(u32, h);
    }
    __syncthreads();
    u32* dst = xq + lvlb + (size_t)(tb * 4 + g) * HW * 32 + (size_t)hw0 * 32;
#pragma unroll
    for (int j = 0; j < 8; ++j) {
      int ow = j * 256 + t;
      int hwl = ow >> 5, ww = ow & 31;
      dst[(size_t)hwl * 32 + ww] = plds[ww * 65 + hwl];
    }
    return;
  }
  if (bx < 8516) {
    int u = bx - 4420;
    int lv = u >> 10;
    int rest = u & 1023;
    int o = rest >> 2, g = rest & 3;
    const float* w = (lv == 0) ? w0 : (lv == 1) ? w1 : (lv == 2) ? w2 : w3;
    const float* src = w + (size_t)(o * 256 + g * 64) * 9;
    float* fl = (float*)plds;
    if (t < 256) { fl[t] = src[t]; fl[t + 256] = src[t + 256]; }
    if (t < 64)  { fl[t + 512] = src[t + 512]; }
    __syncthreads();
    u16* dst = A + (size_t)lv * 589824 + (size_t)o * 2304 + g * 576;
    if (t < 256) {
#pragma unroll
      for (int j = 0; j < 2; ++j) {
        int i = t + j * 256;
        int c = i & 63, p = i >> 6;
        __bf16 bv = (__bf16)fl[c * 9 + p];
        dst[i] = __builtin_bit_cast(u16, bv);
      }
    }
    if (t < 64) {
      int i = t + 512;
      int c = i & 63, p = i >> 6;
      __bf16 bv = (__bf16)fl[c * 9 + p];
      dst[i] = __builtin_bit_cast(u16, bv);
    }
    return;
  }
  {  // float4 copy of x[l] into the concat-output x-slots
    int i = (bx - 8516) * 256 + t;
    const float* xs; int base4, dst4;
    if (i < 524288)      { xs = x0; base4 = 0;      dst4 = 0; }
    else if (i < 655360) { xs = x1; base4 = 524288; dst4 = 1048576; }
    else if (i < 688128) { xs = x2; base4 = 655360; dst4 = 1310720; }
    else if (i < 696320) { xs = x3; base4 = 688128; dst4 = 1376256; }
    else return;
    int local = i - base4;
    ((float4*)out)[(size_t)dst4 + local] = ((const float4*)xs)[local];
  }
}

// ---------------- correlation via MFMA (banded QK^T) + scalar small levels ----------------
// Distance-2 prefetch: 3 LDS buffers; ALL waves issue exactly 4 loads/chunk (dummy for L1
// w>=2 into dead slot); steady state waits vmcnt(4) so chunk ch+1 flies across chunk ch.
__global__ __launch_bounds__(256) void corr_mfma_kernel(const u32* __restrict__ xq, float* __restrict__ corr)
{
  __shared__ __align__(16) u32 lds[12288];   // 3 x 4096-word buffers
  int t = threadIdx.x, bx = blockIdx.x;

  if (bx >= 1472) {  // L2/L3 scalar path
    int gw = ((bx - 1472) * 256 + t) >> 6;
    int lane = t & 63;
    int cs = lane >> 4, hwi = lane & 15;
    int obase = gw * 16;
    int K2, R, DISP, lgW, xqlb, crb, rel;
    if (obase < 41472)      { K2 = 81; R = 9; DISP = 4; lgW = 4; xqlb = 2621440; crb = 2959360; rel = obase; }
    else if (obase < 44672) { K2 = 25; R = 5; DISP = 2; lgW = 3; xqlb = 2752512; crb = 3000832; rel = obase - 41472; }
    else return;
    int W = 1 << lgW, HW = W * W;
    int hw = (rel & (HW - 1)) + hwi;
    int rr = rel >> (2 * lgW);
    int k = rr % K2, b = rr / K2;
    int h = hw >> lgW, wc = hw & (W - 1);
    int dy = k / R - DISP, dx = k % R - DISP;
    int h2 = h + dy, w2 = wc + dx;
    float a = 0.f;
    if ((u32)h2 < (u32)W && (u32)w2 < (u32)W) {
      const u32* q1 = xq + xqlb + ((size_t)((2 + b) * 4 + cs) * HW + hw) * 32;
      const u32* q0 = xq + xqlb + ((size_t)(b * 4 + cs) * HW + (h2 * W + w2)) * 32;
#pragma unroll 8
      for (int j = 0; j < 32; ++j)
        a = __builtin_amdgcn_fdot2(bch(q1[j]), bch(q0[j]), a, false);
    }
    a += __shfl_xor(a, 16);
    a += __shfl_xor(a, 32);
    if (cs == 0) corr[crb + rel + hwi] = a * 0.00390625f;
    return;
  }

  int sbx = (bx & 7) * 184 + (bx >> 3);
  int l = t & 63, w = t >> 6;
  int lvl, b, y, kq, lgW, W, HW, xqlb, crb;
  if (sbx < 1152) { lvl = 0; int r = sbx;        kq = r % 9; r /= 9; y = r & 63; b = r >> 6;
                    lgW = 6; W = 64; HW = 4096; xqlb = 0;       crb = 0; }
  else            { lvl = 1; int r = sbx - 1152; kq = r % 5; r /= 5; y = r & 31; b = r >> 5;
                    lgW = 5; W = 32; HW = 1024; xqlb = 2097152; crb = 2367488; }
  int par, qy, storeok;
  if (lvl == 0) { int rr = w >> 1; par = w & 1; qy = (kq < 8) ? 2 * kq + rr : 16;
                  storeok = !(kq == 8 && w >= 2); }
  else          { par = 0; qy = 4 * kq + w; storeok = (qy <= 16); if (qy > 16) qy = 16; }
  int rowY = (lvl == 0) ? (y + 2 * qy - 16) : (y + qy - 8);
  int f1words = (lvl == 0) ? 1024 : 512;
  int tb1 = 2 + b, tb0 = b;

  bool f1do = (lvl == 0) || (w < 2);
  u32 f1_lo, f1_mask; int f1_dw;
  {
    int G = w * 64 + l;
    int px = G >> 2, s = G & 3;
    int i = px & 31;
    int pari = px >> 5;
    int x = (lvl == 0) ? (2 * i + pari) : px;
    int cg = (s ^ ((i & 3) ^ ((i >> 2) & 3))) & 3;
    if (f1do) {
      f1_lo = (u32)(xqlb + (y * W + x) * 32 + cg * 4);
      f1_dw = w * 256;
      f1_mask = 0xFFFFFFFFu;
    } else {
      f1_lo = 6968960u;                 // offs region (zeros)
      f1_dw = 3584 + (w - 2) * 256;     // dead LDS slot
      f1_mask = 0u;
    }
  }
  u32 f2_lo[3], f2_mask[3]; int f2_dw[3];
#pragma unroll
  for (int q = 0; q < 3; ++q) {
    int F = q * 64 + l;
    int jp = F >> 2, s = F & 3;
    int cg = (s ^ ((jp & 3) ^ ((jp >> 2) & 3))) & 3;
    int xs = (lvl == 0) ? (2 * (jp - 8) + par) : (jp - 8);
    bool valid = ((u32)xs < (u32)W) && ((u32)rowY < (u32)W);
    f2_lo[q]   = valid ? (u32)(xqlb + (rowY * W + xs) * 32 + cg * 4) : 6968960u;
    f2_mask[q] = valid ? 0xFFFFFFFFu : 0u;
    f2_dw[q]   = f1words + w * 768 + q * 256;
  }
  int lr = l & 15, lk = l >> 4;
  int aoff[2], boff[3];
#pragma unroll
  for (int it = 0; it < 2; ++it) {
    int iA = it * 16 + lr;
    int px = ((lvl == 0) ? par * 32 : 0) + iA;
    int phys = (lk ^ ((iA & 3) ^ ((iA >> 2) & 3))) & 3;
    aoff[it] = (px * 16 + phys * 4) * 4;
  }
#pragma unroll
  for (int T = 0; T < 3; ++T) {
    int jp = T * 16 + lr;
    int phys = (lk ^ ((jp & 3) ^ ((jp >> 2) & 3))) & 3;
    boff[T] = (f1words + w * 768 + jp * 16 + phys * 4) * 4;
  }

  f32x4 acc0 = {0,0,0,0}, acc1 = {0,0,0,0}, acc2 = {0,0,0,0}, acc3 = {0,0,0,0};

  auto issue = [&](int ch, int sel) {
    int g2 = ch >> 1, hf = ch & 1;
    u32 cb1 = ((u32)(tb1 * 4 + g2) * (u32)HW) * 32u + (u32)hf * 16u;
    u32 cb0 = ((u32)(tb0 * 4 + g2) * (u32)HW) * 32u + (u32)hf * 16u;
    u32* lb = &lds[sel * 4096];
    __builtin_amdgcn_global_load_lds(xq + ((cb1 & f1_mask) + f1_lo), lb + f1_dw, 16, 0, 0);
#pragma unroll
    for (int q = 0; q < 3; ++q)
      __builtin_amdgcn_global_load_lds(xq + ((cb0 & f2_mask[q]) + f2_lo[q]), lb + f2_dw[q], 16, 0, 0);
  };

  issue(0, 0);
  issue(1, 1);
#pragma unroll 1
  for (int ch = 0; ch < 8; ++ch) {
    if (ch < 7) asm volatile("s_waitcnt vmcnt(4)" ::: "memory");   // drain chunk ch only
    else        asm volatile("s_waitcnt vmcnt(0)" ::: "memory");
    asm volatile("s_barrier" ::: "memory");
    __builtin_amdgcn_sched_barrier(0);
    if (ch + 2 < 8) issue(ch + 2, (ch + 2) % 3);                   // flies across a chunk
    const char* lb = (const char*)&lds[(ch % 3) * 4096];
    f16x8 A0 = *(const f16x8*)(lb + aoff[0]);
    f16x8 A1 = *(const f16x8*)(lb + aoff[1]);
    f16x8 B0 = *(const f16x8*)(lb + boff[0]);
    f16x8 B1 = *(const f16x8*)(lb + boff[1]);
    f16x8 B2 = *(const f16x8*)(lb + boff[2]);
    acc0 = __builtin_amdgcn_mfma_f32_16x16x32_f16(A0, B0, acc0, 0, 0, 0);
    acc1 = __builtin_amdgcn_mfma_f32_16x16x32_f16(A0, B1, acc1, 0, 0, 0);
    acc2 = __builtin_amdgcn_mfma_f32_16x16x32_f16(A1, B1, acc2, 0, 0, 0);
    acc3 = __builtin_amdgcn_mfma_f32_16x16x32_f16(A1, B2, acc3, 0, 0, 0);
  }

  if (!storeok) return;
  const float sc = 0.00390625f;
#pragma unroll
  for (int tile = 0; tile < 4; ++tile) {
    int it = (tile >= 2) ? 1 : 0;
    int T  = (tile == 0) ? 0 : (tile == 3) ? 2 : 1;
    f32x4 av = (tile == 0) ? acc0 : (tile == 1) ? acc1 : (tile == 2) ? acc2 : acc3;
    int jp = T * 16 + lr;
#pragma unroll
    for (int jj = 0; jj < 4; ++jj) {
      int i = it * 16 + lk * 4 + jj;
      int qx = jp - i;
      if (qx >= 0 && qx <= 16) {
        int xo = (lvl == 0) ? (2 * i + par) : i;
        int k = qy * 17 + qx;
        corr[crb + (size_t)(b * 289 + k) * HW + y * W + xo] = av[jj] * sc;
      }
    }
  }
}

// ---------------- offsets: block = 64 px x 4 og-waves; k-split x6; partials or atomics ----
__global__ __launch_bounds__(256) void offset_kernel(
    const float* __restrict__ corr,
    const float* __restrict__ wo0, const float* __restrict__ wo1,
    const float* __restrict__ wo2, const float* __restrict__ wo3,
    float* __restrict__ offs, float* __restrict__ part, int mode)
{
  int t = threadIdx.x, bx = blockIdx.x;
  int kc = bx % 6;
  int unit = bx / 6;                  // 0..169
  int og = t >> 6;                    // wave id
  int lane = t & 63;
  int pxg = unit * 64 + lane;         // 0..10879 (units never straddle levels)

  int b, hw, lgW, K2, crb, ofb;
  const float* wo;
  if (pxg < 8192)       { b = pxg >> 12;        hw = pxg & 4095; lgW = 6; K2 = 289; crb = 0;       ofb = 0;      wo = wo0; }
  else if (pxg < 10240) { int r = pxg - 8192;  b = r >> 10; hw = r & 1023; lgW = 5; K2 = 289; crb = 2367488; ofb = 589824; wo = wo1; }
  else if (pxg < 10752) { int r = pxg - 10240; b = r >> 8;  hw = r & 255;  lgW = 4; K2 = 81;  crb = 2959360; ofb = 737280; wo = wo2; }
  else                  { int r = pxg - 10752; b = r >> 6;  hw = r & 63;   lgW = 3; K2 = 25;  crb = 3000832; ofb = 774144; wo = wo3; }
  int HW = 1 << (2 * lgW);

  int kchunk = (K2 + 5) / 6;
  int klo = kc * kchunk;
  int khi = klo + kchunk; if (khi > K2) khi = K2;
  if (klo >= khi && mode == 0) return;
  if (khi < klo) khi = klo;

  const float* cr = corr + crb + (size_t)b * K2 * HW + hw;
  const float* wp = wo + (size_t)og * 18 * K2;   // wave-uniform base
  float acc[18];
#pragma unroll
  for (int j = 0; j < 18; ++j) acc[j] = 0.f;
#pragma unroll 2
  for (int k = klo; k < khi; ++k) {
    float cv = cr[(size_t)k * HW];                // shared across the 4 og-waves (L1 hit)
#pragma unroll
    for (int j = 0; j < 18; ++j) acc[j] = fmaf(wp[(size_t)j * K2 + k], cv, acc[j]);
  }
  size_t lin = (size_t)ofb + ((size_t)b * 72 + og * 18) * HW + hw;
  if (mode) {
    float* op = part + (size_t)kc * 783360 + lin;
#pragma unroll
    for (int j = 0; j < 18; ++j) op[(size_t)j * HW] = acc[j];
  } else {
    float* op = offs + lin;
#pragma unroll
    for (int j = 0; j < 18; ++j) atomicAdd(&op[(size_t)j * HW], acc[j]);
  }
}

// ---------------- reduce: offs = sum of 6 partials (float4) ----------------
__global__ __launch_bounds__(256) void reduce_kernel(const float* __restrict__ part, float* __restrict__ offs)
{
  int i = blockIdx.x * 256 + threadIdx.x;
  if (i >= 195840) return;
  float4 s = ((const float4*)part)[i];
#pragma unroll
  for (int kc = 1; kc < 6; ++kc) {
    float4 v = ((const float4*)(part + (size_t)kc * 783360))[i];
    s.x += v.x; s.y += v.y; s.z += v.z; s.w += v.w;
  }
  ((float4*)offs)[i] = s;
}

// ---------------- bilinear sampler -> Bbuf rows [r_l][2304] bf16 ----------------
__global__ __launch_bounds__(256) void sample_kernel(
    const u32* __restrict__ xq, const float* __restrict__ offs,
    u16* __restrict__ Bbuf, int Rg0, int nrows)
{
  int bx = blockIdx.x, nbk = gridDim.x;
  int bxs = ((nbk & 7) == 0) ? ((bx & 7) * (nbk >> 3) + (bx >> 3)) : bx;
  int tid = bxs * 256 + threadIdx.x;
  if (tid >= nrows * 144) return;
  int r_l = tid / 144;
  int rem = tid - r_l * 144;
  int gp = rem >> 2, cq = rem & 3;
  int Rg = Rg0 + r_l;
  int b, hw, lgW, xqlb, ofb;
  if (Rg < 8192)       { b = Rg >> 12;       hw = Rg & 4095;  lgW = 6; xqlb = 0;       ofb = 0; }
  else if (Rg < 10240) { int r = Rg - 8192;  b = r >> 10; hw = r & 1023; lgW = 5; xqlb = 2097152; ofb = 589824; }
  else if (Rg < 10752) { int r = Rg - 10240; b = r >> 8;  hw = r & 255;  lgW = 4; xqlb = 2621440; ofb = 737280; }
  else                 { int r = Rg - 10752; b = r >> 6;  hw = r & 63;   lgW = 3; xqlb = 2752512; ofb = 774144; }
  int W = 1 << lgW, HW = W * W;
  u16* rowp = Bbuf + (size_t)r_l * 2304;

  size_t ob = (size_t)ofb + ((size_t)b * 72 + gp * 2) * HW + hw;
  float ody = offs[ob], odx = offs[ob + HW];
  int g = gp / 9, p = gp - g * 9;
  int ky = p / 3, kx = p - ky * 3;
  int sh = hw >> lgW, sw = hw & (W - 1);
  float ys = (float)(sh + ky - 1) + ody;
  float xs = (float)(sw + kx - 1) + odx;
  float y0f = floorf(ys), x0f = floorf(xs);
  float wy = ys - y0f, wx = xs - x0f;
  int y0 = (int)y0f, x0 = (int)x0f, y1 = y0 + 1, x1 = x0 + 1;
  bool vy0 = (u32)y0 < (u32)W, vy1 = (u32)y1 < (u32)W;
  bool vx0 = (u32)x0 < (u32)W, vx1 = (u32)x1 < (u32)W;
  float w00 = (1.f - wy) * (1.f - wx), w01 = (1.f - wy) * wx;
  float w10 = wy * (1.f - wx), w11 = wy * wx;
  const u32* base = xq + xqlb + ((size_t)((2 + b) * 4 + g) * HW) * 32 + cq * 8;
  const uint4 z = make_uint4(0, 0, 0, 0);
  uint4 a00 = z, c00 = z, a01 = z, c01 = z, a10 = z, c10 = z, a11 = z, c11 = z;
  if (vy0 && vx0) { const u32* p0 = base + (size_t)(y0 * W + x0) * 32; a00 = *(const uint4*)p0; c00 = *(const uint4*)(p0 + 4); }
  if (vy0 && vx1) { const u32* p0 = base + (size_t)(y0 * W + x1) * 32; a01 = *(const uint4*)p0; c01 = *(const uint4*)(p0 + 4); }
  if (vy1 && vx0) { const u32* p0 = base + (size_t)(y1 * W + x0) * 32; a10 = *(const uint4*)p0; c10 = *(const uint4*)(p0 + 4); }
  if (vy1 && vx1) { const u32* p0 = base + (size_t)(y1 * W + x1) * 32; a11 = *(const uint4*)p0; c11 = *(const uint4*)(p0 + 4); }
  bf16x8 r0, r1;
#pragma unroll
  for (int ww = 0; ww < 4; ++ww) {
    f16x2 h00 = bch(((const u32*)&a00)[ww]);
    f16x2 h01 = bch(((const u32*)&a01)[ww]);
    f16x2 h10 = bch(((const u32*)&a10)[ww]);
    f16x2 h11 = bch(((const u32*)&a11)[ww]);
    float lo = w00 * (float)h00[0] + w01 * (float)h01[0] + w10 * (float)h10[0] + w11 * (float)h11[0];
    float hi = w00 * (float)h00[1] + w01 * (float)h01[1] + w10 * (float)h10[1] + w11 * (float)h11[1];
    r0[2 * ww] = (__bf16)lo; r0[2 * ww + 1] = (__bf16)hi;
  }
#pragma unroll
  for (int ww = 0; ww < 4; ++ww) {
    f16x2 h00 = bch(((const u32*)&c00)[ww]);
    f16x2 h01 = bch(((const u32*)&c01)[ww]);
    f16x2 h10 = bch(((const u32*)&c10)[ww]);
    f16x2 h11 = bch(((const u32*)&c11)[ww]);
    float lo = w00 * (float)h00[0] + w01 * (float)h01[0] + w10 * (float)h10[0] + w11 * (float)h11[0];
    float hi = w00 * (float)h00[1] + w01 * (float)h01[1] + w10 * (float)h10[1] + w11 * (float)h11[1];
    r1[2 * ww] = (__bf16)lo; r1[2 * ww + 1] = (__bf16)hi;
  }
  u16* dst = rowp + gp * 64 + cq * 16;
  *(bf16x8*)dst = r0;
  *(bf16x8*)(dst + 8) = r1;
}

// ---------------- GEMM v5: BM=64, BN=64, BK=64; dbuf LDS; distance-2 reg prefetch ------
#define G_ISSUE(P, kt) { const uint4* as_ = (const uint4*)(Asrc + (kt) * 64); \
                         const uint4* bs_ = (const uint4*)(Bsrc + (kt) * 64); \
                         a0##P = as_[0]; a1##P = as_[1]; b0##P = bs_[0]; b1##P = bs_[1]; }
#define G_COMMIT(P, sel) { *(uint4*)(&Al[sel][srow * 72 + sc4 * 16]) = a0##P; \
                           *(uint4*)(&Al[sel][srow * 72 + sc4 * 16 + 8]) = a1##P; \
                           *(uint4*)(&Bl[sel][srow * 72 + sc4 * 16]) = b0##P; \
                           *(uint4*)(&Bl[sel][srow * 72 + sc4 * 16 + 8]) = b1##P; }
#define G_MFMA(sel) { _Pragma("unroll") \
  for (int kk = 0; kk < 2; ++kk) { \
    bf16x8 fb0 = *(const bf16x8*)(&Bl[sel][(wvc * 32 + lr) * 72 + kk * 32 + lk * 8]); \
    bf16x8 fb1 = *(const bf16x8*)(&Bl[sel][(wvc * 32 + 16 + lr) * 72 + kk * 32 + lk * 8]); \
    bf16x8 fa0 = *(const bf16x8*)(&Al[sel][(wvr * 32 + lr) * 72 + kk * 32 + lk * 8]); \
    bf16x8 fa1 = *(const bf16x8*)(&Al[sel][(wvr * 32 + 16 + lr) * 72 + kk * 32 + lk * 8]); \
    acc[0][0] = __builtin_amdgcn_mfma_f32_16x16x32_bf16(fa0, fb0, acc[0][0], 0, 0, 0); \
    acc[0][1] = __builtin_amdgcn_mfma_f32_16x16x32_bf16(fa0, fb1, acc[0][1], 0, 0, 0); \
    acc[1][0] = __builtin_amdgcn_mfma_f32_16x16x32_bf16(fa1, fb0, acc[1][0], 0, 0, 0); \
    acc[1][1] = __builtin_amdgcn_mfma_f32_16x16x32_bf16(fa1, fb1, acc[1][1], 0, 0, 0); \
  } }

__global__ __launch_bounds__(256) void gemm2_kernel(
    const u16* __restrict__ A, const u16* __restrict__ Bbuf,
    int Rg0, float* __restrict__ out)
{
  __shared__ __align__(16) u16 Al[2][64 * 72];
  __shared__ __align__(16) u16 Bl[2][64 * 72];
  int t = threadIdx.x, bx = blockIdx.x;
  int nb = gridDim.x;
  int gsw = (bx & 7) * (nb >> 3) + (bx >> 3);
  int mt = gsw & 3, nt = gsw >> 2;
  int Rgt = Rg0 + nt * 64;
  int b, hw0, lgW, Ab, outb;
  if (Rgt < 8192)       { b = Rgt >> 12;       hw0 = Rgt & 4095;  lgW = 6; Ab = 0;       outb = 2097152; }
  else if (Rgt < 10240) { int r = Rgt - 8192;  b = r >> 10; hw0 = r & 1023; lgW = 5; Ab = 589824;  outb = 4718592; }
  else if (Rgt < 10752) { int r = Rgt - 10240; b = r >> 8;  hw0 = r & 255;  lgW = 4; Ab = 1179648; outb = 5373952; }
  else                  { int r = Rgt - 10752; b = r >> 6;  hw0 = r & 63;   lgW = 3; Ab = 1769472; outb = 5537792; }
  int HW = 1 << (2 * lgW);
  const u16* Bbase = Bbuf + (size_t)(Rgt - Rg0) * 2304;

  int o0 = mt * 64;
  int l = t & 63, wv = t >> 6;
  int lr = l & 15, lk = l >> 4;
  int wvr = wv >> 1, wvc = wv & 1;

  int srow = t >> 2, sc4 = t & 3;
  const u16* Asrc = A + Ab + (size_t)(o0 + srow) * 2304 + sc4 * 16;
  const u16* Bsrc = Bbase + (size_t)srow * 2304 + sc4 * 16;

  f32x4 acc[2][2];
#pragma unroll
  for (int i = 0; i < 2; ++i)
#pragma unroll
    for (int j = 0; j < 2; ++j) acc[i][j] = (f32x4){0, 0, 0, 0};

  uint4 a0A, a1A, b0A, b1A, a0B, a1B, b0B, b1B;

  G_ISSUE(A, 0); G_COMMIT(A, 0);
  G_ISSUE(B, 1);
  G_ISSUE(A, 2);
  __syncthreads();
#pragma unroll 1
  for (int k2 = 0; k2 < 18; ++k2) {
    int kt = 2 * k2;
    G_MFMA(0);
    if (kt < 35) G_COMMIT(B, 1);
    __syncthreads();
    if (kt + 3 < 36) G_ISSUE(B, kt + 3);
    G_MFMA(1);
    if (kt + 1 < 35) G_COMMIT(A, 0);
    __syncthreads();
    if (kt + 4 < 36) G_ISSUE(A, kt + 4);
  }

  float* op = out + outb + (size_t)b * 256 * HW;
#pragma unroll
  for (int ar = 0; ar < 2; ++ar)
#pragma unroll
    for (int bc = 0; bc < 2; ++bc)
#pragma unroll
      for (int j = 0; j < 4; ++j) {
        int orow = o0 + wvr * 32 + ar * 16 + lk * 4 + j;
        int col = hw0 + wvc * 32 + bc * 16 + lr;
        op[(size_t)orow * HW + col] = fmaxf(acc[ar][bc][j], 0.f);
      }
}

extern "C" void kernel_launch(void* const* d_in, const int* in_sizes, int n_in,
                              void* d_out, int out_size, void* d_ws, size_t ws_size,
                              hipStream_t stream) {
  const float* x[4];
  const float* woff[4];
  const float* wad[4];
  for (int l = 0; l < 4; ++l) {
    x[l]    = (const float*)d_in[l];
    woff[l] = (const float*)d_in[4 + 2 * l];
    wad[l]  = (const float*)d_in[5 + 2 * l];
  }
  float* out = (float*)d_out;
  char* ws = (char*)d_ws;
  u32*   xq   = (u32*)(ws);
  u16*   A    = (u16*)(ws + 11141120);
  float* corr = (float*)(ws + 15859712);
  float* offs = (float*)(ws + 27875840);
  float* part = (float*)(ws + 31009280);
  u16* BbufS = (u16*)(ws + 15859712);
  u16* BbufL = (u16*)(ws + 31009280);
  int big  = (ws_size >= (size_t)81144320) ? 1 : 0;
  int part_ok = (ws_size >= (size_t)(31009280 + 18800640)) ? 1 : 0;

  prep_kernel<<<11236, 256, 0, stream>>>(x[0], x[1], x[2], x[3],
                                         wad[0], wad[1], wad[2], wad[3], xq, A, offs, out);
  corr_mfma_kernel<<<2170, 256, 0, stream>>>(xq, corr);
  offset_kernel<<<1020, 256, 0, stream>>>(corr, woff[0], woff[1], woff[2], woff[3],
                                          offs, part, part_ok);
  if (part_ok)
    reduce_kernel<<<765, 256, 0, stream>>>(part, offs);

  if (big) {
    sample_kernel<<<6120, 256, 0, stream>>>(xq, offs, BbufL, 0, 10880);
    gemm2_kernel<<<680, 256, 0, stream>>>(A, BbufL, 0, out);
  } else {
    for (int ph = 0; ph < 5; ++ph) {
      int Rg0 = ph * 2560;
      int nrows = (ph < 4) ? 2560 : 640;
      int sgrid = (nrows * 144 + 255) / 256;
      int ggrid = (nrows / 64) * 4;
      sample_kernel<<<sgrid, 256, 0, stream>>>(xq, offs, BbufS, Rg0, nrows);
      gemm2_kernel<<<ggrid, 256, 0, stream>>>(A, BbufS, Rg0, out);
    }
  }
}

// Round 22
// 115.623 us; speedup vs baseline: 1.3291x; 1.3291x over previous
//
#include <hip/hip_runtime.h>

typedef unsigned int u32;
typedef unsigned short u16;
typedef _Float16 f16x2 __attribute__((ext_vector_type(2)));
typedef _Float16 f16x8 __attribute__((ext_vector_type(8)));
typedef __bf16 bf16x8 __attribute__((ext_vector_type(8)));
typedef float f32x4 __attribute__((ext_vector_type(4)));

static __device__ __forceinline__ f16x2 bch(u32 u) { return __builtin_bit_cast(f16x2, u); }

// ---------------- ws layout (bytes) ----------------
// xq   (u32)  @ 0         : f16x2 pixel-major, [lvl][tb 4][g 4][hw][32 words]
// A    (u16)  @ 11141120  : bf16 weights [lvl][o 256][k 2304], k=(g*9+p)*64+c
// corr (f32)  @ 15859712  : [lvl][b][K2][HW]; dead after offset -> small-mode B buffer
// offs (f32)  @ 27875840  : [lvl][b][72][HW], 783360 floats (zero during corr = OOB scratch)
// part (f32)  @ 31009280  : 6 x 783360 partials (18.8 MB); dead after reduce ->
// big-mode B buffer @ 31009280: 10880 rows x 2304 bf16 (needs ws >= 81,144,320)

// ---------------- merged preamble: zero offs + pack + aconv(transposed) + out-copy(f4) ---
__global__ __launch_bounds__(256) void prep_kernel(
    const float* __restrict__ x0, const float* __restrict__ x1,
    const float* __restrict__ x2, const float* __restrict__ x3,
    const float* __restrict__ w0, const float* __restrict__ w1,
    const float* __restrict__ w2, const float* __restrict__ w3,
    u32* __restrict__ xq, u16* __restrict__ A, float* __restrict__ offs,
    float* __restrict__ out)
{
  __shared__ u32 plds[32 * 65];
  int bx = blockIdx.x, t = threadIdx.x;
  if (bx < 3060) {
    int i = bx * 256 + t;
    if (i < 783360) offs[i] = 0.f;
    return;
  }
  if (bx < 4420) {
    int local = bx - 3060;
    const float* xs; int lvlb, lgW, lgnch;
    if (local < 1024)      { xs = x0; lvlb = 0;       lgW = 6; lgnch = 6; }
    else if (local < 1280) { xs = x1; lvlb = 2097152; lgW = 5; lgnch = 4; local -= 1024; }
    else if (local < 1344) { xs = x2; lvlb = 2621440; lgW = 4; lgnch = 2; local -= 1280; }
    else                   { xs = x3; lvlb = 2752512; lgW = 3; lgnch = 0; local -= 1344; }
    int HW = 1 << (2 * lgW);
    int hc = local & ((1 << lgnch) - 1);
    int g  = (local >> lgnch) & 3;
    int tb = local >> (lgnch + 2);
    int hw0 = hc * 64;
    int lane = t & 63, qd = t >> 6;
#pragma unroll
    for (int j = 0; j < 8; ++j) {
      int cpw = qd * 8 + j;
      int c = tb * 256 + g * 64 + cpw * 2;
      const float* s = xs + (size_t)c * HW + hw0 + lane;
      float f0 = s[0], f1 = s[HW];
      f16x2 h; h[0] = (_Float16)f0; h[1] = (_Float16)f1;
      plds[cpw * 65 + lane] = __builtin_bit_cast(u32, h);
    }
    __syncthreads();
    u32* dst = xq + lvlb + (size_t)(tb * 4 + g) * HW * 32 + (size_t)hw0 * 32;
#pragma unroll
    for (int j = 0; j < 8; ++j) {
      int ow = j * 256 + t;
      int hwl = ow >> 5, ww = ow & 31;
      dst[(size_t)hwl * 32 + ww] = plds[ww * 65 + hwl];
    }
    return;
  }
  if (bx < 8516) {
    int u = bx - 4420;
    int lv = u >> 10;
    int rest = u & 1023;
    int o = rest >> 2, g = rest & 3;
    const float* w = (lv == 0) ? w0 : (lv == 1) ? w1 : (lv == 2) ? w2 : w3;
    const float* src = w + (size_t)(o * 256 + g * 64) * 9;
    float* fl = (float*)plds;
    if (t < 256) { fl[t] = src[t]; fl[t + 256] = src[t + 256]; }
    if (t < 64)  { fl[t + 512] = src[t + 512]; }
    __syncthreads();
    u16* dst = A + (size_t)lv * 589824 + (size_t)o * 2304 + g * 576;
    if (t < 256) {
#pragma unroll
      for (int j = 0; j < 2; ++j) {
        int i = t + j * 256;
        int c = i & 63, p = i >> 6;
        __bf16 bv = (__bf16)fl[c * 9 + p];
        dst[i] = __builtin_bit_cast(u16, bv);
      }
    }
    if (t < 64) {
      int i = t + 512;
      int c = i & 63, p = i >> 6;
      __bf16 bv = (__bf16)fl[c * 9 + p];
      dst[i] = __builtin_bit_cast(u16, bv);
    }
    return;
  }
  {  // float4 copy of x[l] into the concat-output x-slots
    int i = (bx - 8516) * 256 + t;
    const float* xs; int base4, dst4;
    if (i < 524288)      { xs = x0; base4 = 0;      dst4 = 0; }
    else if (i < 655360) { xs = x1; base4 = 524288; dst4 = 1048576; }
    else if (i < 688128) { xs = x2; base4 = 655360; dst4 = 1310720; }
    else if (i < 696320) { xs = x3; base4 = 688128; dst4 = 1376256; }
    else return;
    int local = i - base4;
    ((float4*)out)[(size_t)dst4 + local] = ((const float4*)xs)[local];
  }
}

// ---------------- correlation via MFMA (banded QK^T) + scalar small levels ----------------
// Distance-2 prefetch: 3 LDS buffers; ALL waves issue exactly 4 loads/chunk (dummy for L1
// w>=2 into dead slot); steady state waits vmcnt(4) so chunk ch+1 flies across chunk ch.
__global__ __launch_bounds__(256) void corr_mfma_kernel(const u32* __restrict__ xq, float* __restrict__ corr)
{
  __shared__ __align__(16) u32 lds[12288];   // 3 x 4096-word buffers
  int t = threadIdx.x, bx = blockIdx.x;

  if (bx >= 1472) {  // L2/L3 scalar path
    int gw = ((bx - 1472) * 256 + t) >> 6;
    int lane = t & 63;
    int cs = lane >> 4, hwi = lane & 15;
    int obase = gw * 16;
    int K2, R, DISP, lgW, xqlb, crb, rel;
    if (obase < 41472)      { K2 = 81; R = 9; DISP = 4; lgW = 4; xqlb = 2621440; crb = 2959360; rel = obase; }
    else if (obase < 44672) { K2 = 25; R = 5; DISP = 2; lgW = 3; xqlb = 2752512; crb = 3000832; rel = obase - 41472; }
    else return;
    int W = 1 << lgW, HW = W * W;
    int hw = (rel & (HW - 1)) + hwi;
    int rr = rel >> (2 * lgW);
    int k = rr % K2, b = rr / K2;
    int h = hw >> lgW, wc = hw & (W - 1);
    int dy = k / R - DISP, dx = k % R - DISP;
    int h2 = h + dy, w2 = wc + dx;
    float a = 0.f;
    if ((u32)h2 < (u32)W && (u32)w2 < (u32)W) {
      const u32* q1 = xq + xqlb + ((size_t)((2 + b) * 4 + cs) * HW + hw) * 32;
      const u32* q0 = xq + xqlb + ((size_t)(b * 4 + cs) * HW + (h2 * W + w2)) * 32;
#pragma unroll 8
      for (int j = 0; j < 32; ++j)
        a = __builtin_amdgcn_fdot2(bch(q1[j]), bch(q0[j]), a, false);
    }
    a += __shfl_xor(a, 16);
    a += __shfl_xor(a, 32);
    if (cs == 0) corr[crb + rel + hwi] = a * 0.00390625f;
    return;
  }

  int sbx = (bx & 7) * 184 + (bx >> 3);
  int l = t & 63, w = t >> 6;
  int lvl, b, y, kq, lgW, W, HW, xqlb, crb;
  if (sbx < 1152) { lvl = 0; int r = sbx;        kq = r % 9; r /= 9; y = r & 63; b = r >> 6;
                    lgW = 6; W = 64; HW = 4096; xqlb = 0;       crb = 0; }
  else            { lvl = 1; int r = sbx - 1152; kq = r % 5; r /= 5; y = r & 31; b = r >> 5;
                    lgW = 5; W = 32; HW = 1024; xqlb = 2097152; crb = 2367488; }
  int par, qy, storeok;
  if (lvl == 0) { int rr = w >> 1; par = w & 1; qy = (kq < 8) ? 2 * kq + rr : 16;
                  storeok = !(kq == 8 && w >= 2); }
  else          { par = 0; qy = 4 * kq + w; storeok = (qy <= 16); if (qy > 16) qy = 16; }
  int rowY = (lvl == 0) ? (y + 2 * qy - 16) : (y + qy - 8);
  int f1words = (lvl == 0) ? 1024 : 512;
  int tb1 = 2 + b, tb0 = b;

  bool f1do = (lvl == 0) || (w < 2);
  u32 f1_lo, f1_mask; int f1_dw;
  {
    int G = w * 64 + l;
    int px = G >> 2, s = G & 3;
    int i = px & 31;
    int pari = px >> 5;
    int x = (lvl == 0) ? (2 * i + pari) : px;
    int cg = (s ^ ((i & 3) ^ ((i >> 2) & 3))) & 3;
    if (f1do) {
      f1_lo = (u32)(xqlb + (y * W + x) * 32 + cg * 4);
      f1_dw = w * 256;
      f1_mask = 0xFFFFFFFFu;
    } else {
      f1_lo = 6968960u;                 // offs region (zeros)
      f1_dw = 3584 + (w - 2) * 256;     // dead LDS slot
      f1_mask = 0u;
    }
  }
  u32 f2_lo[3], f2_mask[3]; int f2_dw[3];
#pragma unroll
  for (int q = 0; q < 3; ++q) {
    int F = q * 64 + l;
    int jp = F >> 2, s = F & 3;
    int cg = (s ^ ((jp & 3) ^ ((jp >> 2) & 3))) & 3;
    int xs = (lvl == 0) ? (2 * (jp - 8) + par) : (jp - 8);
    bool valid = ((u32)xs < (u32)W) && ((u32)rowY < (u32)W);
    f2_lo[q]   = valid ? (u32)(xqlb + (rowY * W + xs) * 32 + cg * 4) : 6968960u;
    f2_mask[q] = valid ? 0xFFFFFFFFu : 0u;
    f2_dw[q]   = f1words + w * 768 + q * 256;
  }
  int lr = l & 15, lk = l >> 4;
  int aoff[2], boff[3];
#pragma unroll
  for (int it = 0; it < 2; ++it) {
    int iA = it * 16 + lr;
    int px = ((lvl == 0) ? par * 32 : 0) + iA;
    int phys = (lk ^ ((iA & 3) ^ ((iA >> 2) & 3))) & 3;
    aoff[it] = (px * 16 + phys * 4) * 4;
  }
#pragma unroll
  for (int T = 0; T < 3; ++T) {
    int jp = T * 16 + lr;
    int phys = (lk ^ ((jp & 3) ^ ((jp >> 2) & 3))) & 3;
    boff[T] = (f1words + w * 768 + jp * 16 + phys * 4) * 4;
  }

  f32x4 acc0 = {0,0,0,0}, acc1 = {0,0,0,0}, acc2 = {0,0,0,0}, acc3 = {0,0,0,0};

  auto issue = [&](int ch, int sel) {
    int g2 = ch >> 1, hf = ch & 1;
    u32 cb1 = ((u32)(tb1 * 4 + g2) * (u32)HW) * 32u + (u32)hf * 16u;
    u32 cb0 = ((u32)(tb0 * 4 + g2) * (u32)HW) * 32u + (u32)hf * 16u;
    u32* lb = &lds[sel * 4096];
    __builtin_amdgcn_global_load_lds(xq + ((cb1 & f1_mask) + f1_lo), lb + f1_dw, 16, 0, 0);
#pragma unroll
    for (int q = 0; q < 3; ++q)
      __builtin_amdgcn_global_load_lds(xq + ((cb0 & f2_mask[q]) + f2_lo[q]), lb + f2_dw[q], 16, 0, 0);
  };

  issue(0, 0);
  issue(1, 1);
#pragma unroll 1
  for (int ch = 0; ch < 8; ++ch) {
    if (ch < 7) asm volatile("s_waitcnt vmcnt(4)" ::: "memory");   // drain chunk ch only
    else        asm volatile("s_waitcnt vmcnt(0)" ::: "memory");
    asm volatile("s_barrier" ::: "memory");
    __builtin_amdgcn_sched_barrier(0);
    if (ch + 2 < 8) issue(ch + 2, (ch + 2) % 3);                   // flies across a chunk
    const char* lb = (const char*)&lds[(ch % 3) * 4096];
    f16x8 A0 = *(const f16x8*)(lb + aoff[0]);
    f16x8 A1 = *(const f16x8*)(lb + aoff[1]);
    f16x8 B0 = *(const f16x8*)(lb + boff[0]);
    f16x8 B1 = *(const f16x8*)(lb + boff[1]);
    f16x8 B2 = *(const f16x8*)(lb + boff[2]);
    acc0 = __builtin_amdgcn_mfma_f32_16x16x32_f16(A0, B0, acc0, 0, 0, 0);
    acc1 = __builtin_amdgcn_mfma_f32_16x16x32_f16(A0, B1, acc1, 0, 0, 0);
    acc2 = __builtin_amdgcn_mfma_f32_16x16x32_f16(A1, B1, acc2, 0, 0, 0);
    acc3 = __builtin_amdgcn_mfma_f32_16x16x32_f16(A1, B2, acc3, 0, 0, 0);
  }

  if (!storeok) return;
  const float sc = 0.00390625f;
#pragma unroll
  for (int tile = 0; tile < 4; ++tile) {
    int it = (tile >= 2) ? 1 : 0;
    int T  = (tile == 0) ? 0 : (tile == 3) ? 2 : 1;
    f32x4 av = (tile == 0) ? acc0 : (tile == 1) ? acc1 : (tile == 2) ? acc2 : acc3;
    int jp = T * 16 + lr;
#pragma unroll
    for (int jj = 0; jj < 4; ++jj) {
      int i = it * 16 + lk * 4 + jj;
      int qx = jp - i;
      if (qx >= 0 && qx <= 16) {
        int xo = (lvl == 0) ? (2 * i + par) : i;
        int k = qy * 17 + qx;
        corr[crb + (size_t)(b * 289 + k) * HW + y * W + xo] = av[jj] * sc;
      }
    }
  }
}

// ---------------- offsets: og in blockIdx (block-uniform weights); k-split x6 ------------
__global__ __launch_bounds__(256) void offset_kernel(
    const float* __restrict__ corr,
    const float* __restrict__ wo0, const float* __restrict__ wo1,
    const float* __restrict__ wo2, const float* __restrict__ wo3,
    float* __restrict__ offs, float* __restrict__ part, int mode)
{
  int t = threadIdx.x, bx = blockIdx.x;
  int kc = bx % 6;
  int unit = bx / 6;
  int og = unit & 3;
  int pb = unit >> 2;

  int lgW, K2, crb, ofb, pbl;
  const float* wo;
  if (pb < 32)      { pbl = pb;      lgW = 6; K2 = 289; crb = 0;       ofb = 0;      wo = wo0; }
  else if (pb < 40) { pbl = pb - 32; lgW = 5; K2 = 289; crb = 2367488; ofb = 589824; wo = wo1; }
  else if (pb < 42) { pbl = pb - 40; lgW = 4; K2 = 81;  crb = 2959360; ofb = 737280; wo = wo2; }
  else              { pbl = 0;       lgW = 3; K2 = 25;  crb = 3000832; ofb = 774144; wo = wo3; }
  int HW = 1 << (2 * lgW);
  int pxg = pbl * 256 + t;
  if (lgW == 3 && t >= 128) return;
  int b = pxg >> (2 * lgW);
  int hw = pxg & (HW - 1);

  int kchunk = (K2 + 5) / 6;
  int klo = kc * kchunk;
  int khi = klo + kchunk; if (khi > K2) khi = K2;
  if (klo >= khi && mode == 0) return;
  if (khi < klo) khi = klo;

  const float* cr = corr + crb + (size_t)b * K2 * HW + hw;
  const float* wp = wo + (size_t)og * 18 * K2;   // block-uniform base -> scalar loads
  float acc[18];
#pragma unroll
  for (int j = 0; j < 18; ++j) acc[j] = 0.f;
#pragma unroll 2
  for (int k = klo; k < khi; ++k) {
    float cv = cr[(size_t)k * HW];
#pragma unroll
    for (int j = 0; j < 18; ++j) acc[j] = fmaf(wp[(size_t)j * K2 + k], cv, acc[j]);
  }
  size_t lin = (size_t)ofb + ((size_t)b * 72 + og * 18) * HW + hw;
  if (mode) {
    float* op = part + (size_t)kc * 783360 + lin;
#pragma unroll
    for (int j = 0; j < 18; ++j) op[(size_t)j * HW] = acc[j];
  } else {
    float* op = offs + lin;
#pragma unroll
    for (int j = 0; j < 18; ++j) atomicAdd(&op[(size_t)j * HW], acc[j]);
  }
}

// ---------------- reduce: offs = sum of 6 partials (float4) ----------------
__global__ __launch_bounds__(256) void reduce_kernel(const float* __restrict__ part, float* __restrict__ offs)
{
  int i = blockIdx.x * 256 + threadIdx.x;
  if (i >= 195840) return;
  float4 s = ((const float4*)part)[i];
#pragma unroll
  for (int kc = 1; kc < 6; ++kc) {
    float4 v = ((const float4*)(part + (size_t)kc * 783360))[i];
    s.x += v.x; s.y += v.y; s.z += v.z; s.w += v.w;
  }
  ((float4*)offs)[i] = s;
}

// ---------------- bilinear sampler -> Bbuf rows [r_l][2304] bf16 ----------------
__global__ __launch_bounds__(256) void sample_kernel(
    const u32* __restrict__ xq, const float* __restrict__ offs,
    u16* __restrict__ Bbuf, int Rg0, int nrows)
{
  int bx = blockIdx.x, nbk = gridDim.x;
  int bxs = ((nbk & 7) == 0) ? ((bx & 7) * (nbk >> 3) + (bx >> 3)) : bx;
  int tid = bxs * 256 + threadIdx.x;
  if (tid >= nrows * 144) return;
  int r_l = tid / 144;
  int rem = tid - r_l * 144;
  int gp = rem >> 2, cq = rem & 3;
  int Rg = Rg0 + r_l;
  int b, hw, lgW, xqlb, ofb;
  if (Rg < 8192)       { b = Rg >> 12;       hw = Rg & 4095;  lgW = 6; xqlb = 0;       ofb = 0; }
  else if (Rg < 10240) { int r = Rg - 8192;  b = r >> 10; hw = r & 1023; lgW = 5; xqlb = 2097152; ofb = 589824; }
  else if (Rg < 10752) { int r = Rg - 10240; b = r >> 8;  hw = r & 255;  lgW = 4; xqlb = 2621440; ofb = 737280; }
  else                 { int r = Rg - 10752; b = r >> 6;  hw = r & 63;   lgW = 3; xqlb = 2752512; ofb = 774144; }
  int W = 1 << lgW, HW = W * W;
  u16* rowp = Bbuf + (size_t)r_l * 2304;

  size_t ob = (size_t)ofb + ((size_t)b * 72 + gp * 2) * HW + hw;
  float ody = offs[ob], odx = offs[ob + HW];
  int g = gp / 9, p = gp - g * 9;
  int ky = p / 3, kx = p - ky * 3;
  int sh = hw >> lgW, sw = hw & (W - 1);
  float ys = (float)(sh + ky - 1) + ody;
  float xs = (float)(sw + kx - 1) + odx;
  float y0f = floorf(ys), x0f = floorf(xs);
  float wy = ys - y0f, wx = xs - x0f;
  int y0 = (int)y0f, x0 = (int)x0f, y1 = y0 + 1, x1 = x0 + 1;
  bool vy0 = (u32)y0 < (u32)W, vy1 = (u32)y1 < (u32)W;
  bool vx0 = (u32)x0 < (u32)W, vx1 = (u32)x1 < (u32)W;
  float w00 = (1.f - wy) * (1.f - wx), w01 = (1.f - wy) * wx;
  float w10 = wy * (1.f - wx), w11 = wy * wx;
  const u32* base = xq + xqlb + ((size_t)((2 + b) * 4 + g) * HW) * 32 + cq * 8;
  const uint4 z = make_uint4(0, 0, 0, 0);
  uint4 a00 = z, c00 = z, a01 = z, c01 = z, a10 = z, c10 = z, a11 = z, c11 = z;
  if (vy0 && vx0) { const u32* p0 = base + (size_t)(y0 * W + x0) * 32; a00 = *(const uint4*)p0; c00 = *(const uint4*)(p0 + 4); }
  if (vy0 && vx1) { const u32* p0 = base + (size_t)(y0 * W + x1) * 32; a01 = *(const uint4*)p0; c01 = *(const uint4*)(p0 + 4); }
  if (vy1 && vx0) { const u32* p0 = base + (size_t)(y1 * W + x0) * 32; a10 = *(const uint4*)p0; c10 = *(const uint4*)(p0 + 4); }
  if (vy1 && vx1) { const u32* p0 = base + (size_t)(y1 * W + x1) * 32; a11 = *(const uint4*)p0; c11 = *(const uint4*)(p0 + 4); }
  bf16x8 r0, r1;
#pragma unroll
  for (int ww = 0; ww < 4; ++ww) {
    f16x2 h00 = bch(((const u32*)&a00)[ww]);
    f16x2 h01 = bch(((const u32*)&a01)[ww]);
    f16x2 h10 = bch(((const u32*)&a10)[ww]);
    f16x2 h11 = bch(((const u32*)&a11)[ww]);
    float lo = w00 * (float)h00[0] + w01 * (float)h01[0] + w10 * (float)h10[0] + w11 * (float)h11[0];
    float hi = w00 * (float)h00[1] + w01 * (float)h01[1] + w10 * (float)h10[1] + w11 * (float)h11[1];
    r0[2 * ww] = (__bf16)lo; r0[2 * ww + 1] = (__bf16)hi;
  }
#pragma unroll
  for (int ww = 0; ww < 4; ++ww) {
    f16x2 h00 = bch(((const u32*)&c00)[ww]);
    f16x2 h01 = bch(((const u32*)&c01)[ww]);
    f16x2 h10 = bch(((const u32*)&c10)[ww]);
    f16x2 h11 = bch(((const u32*)&c11)[ww]);
    float lo = w00 * (float)h00[0] + w01 * (float)h01[0] + w10 * (float)h10[0] + w11 * (float)h11[0];
    float hi = w00 * (float)h00[1] + w01 * (float)h01[1] + w10 * (float)h10[1] + w11 * (float)h11[1];
    r1[2 * ww] = (__bf16)lo; r1[2 * ww + 1] = (__bf16)hi;
  }
  u16* dst = rowp + gp * 64 + cq * 16;
  *(bf16x8*)dst = r0;
  *(bf16x8*)(dst + 8) = r1;
}

// ---------------- GEMM v5: BM=64, BN=64, BK=64; dbuf LDS; distance-2 reg prefetch ------
#define G_ISSUE(P, kt) { const uint4* as_ = (const uint4*)(Asrc + (kt) * 64); \
                         const uint4* bs_ = (const uint4*)(Bsrc + (kt) * 64); \
                         a0##P = as_[0]; a1##P = as_[1]; b0##P = bs_[0]; b1##P = bs_[1]; }
#define G_COMMIT(P, sel) { *(uint4*)(&Al[sel][srow * 72 + sc4 * 16]) = a0##P; \
                           *(uint4*)(&Al[sel][srow * 72 + sc4 * 16 + 8]) = a1##P; \
                           *(uint4*)(&Bl[sel][srow * 72 + sc4 * 16]) = b0##P; \
                           *(uint4*)(&Bl[sel][srow * 72 + sc4 * 16 + 8]) = b1##P; }
#define G_MFMA(sel) { _Pragma("unroll") \
  for (int kk = 0; kk < 2; ++kk) { \
    bf16x8 fb0 = *(const bf16x8*)(&Bl[sel][(wvc * 32 + lr) * 72 + kk * 32 + lk * 8]); \
    bf16x8 fb1 = *(const bf16x8*)(&Bl[sel][(wvc * 32 + 16 + lr) * 72 + kk * 32 + lk * 8]); \
    bf16x8 fa0 = *(const bf16x8*)(&Al[sel][(wvr * 32 + lr) * 72 + kk * 32 + lk * 8]); \
    bf16x8 fa1 = *(const bf16x8*)(&Al[sel][(wvr * 32 + 16 + lr) * 72 + kk * 32 + lk * 8]); \
    acc[0][0] = __builtin_amdgcn_mfma_f32_16x16x32_bf16(fa0, fb0, acc[0][0], 0, 0, 0); \
    acc[0][1] = __builtin_amdgcn_mfma_f32_16x16x32_bf16(fa0, fb1, acc[0][1], 0, 0, 0); \
    acc[1][0] = __builtin_amdgcn_mfma_f32_16x16x32_bf16(fa1, fb0, acc[1][0], 0, 0, 0); \
    acc[1][1] = __builtin_amdgcn_mfma_f32_16x16x32_bf16(fa1, fb1, acc[1][1], 0, 0, 0); \
  } }

__global__ __launch_bounds__(256) void gemm2_kernel(
    const u16* __restrict__ A, const u16* __restrict__ Bbuf,
    int Rg0, float* __restrict__ out)
{
  __shared__ __align__(16) u16 Al[2][64 * 72];
  __shared__ __align__(16) u16 Bl[2][64 * 72];
  int t = threadIdx.x, bx = blockIdx.x;
  int nb = gridDim.x;
  int gsw = (bx & 7) * (nb >> 3) + (bx >> 3);
  int mt = gsw & 3, nt = gsw >> 2;
  int Rgt = Rg0 + nt * 64;
  int b, hw0, lgW, Ab, outb;
  if (Rgt < 8192)       { b = Rgt >> 12;       hw0 = Rgt & 4095;  lgW = 6; Ab = 0;       outb = 2097152; }
  else if (Rgt < 10240) { int r = Rgt - 8192;  b = r >> 10; hw0 = r & 1023; lgW = 5; Ab = 589824;  outb = 4718592; }
  else if (Rgt < 10752) { int r = Rgt - 10240; b = r >> 8;  hw0 = r & 255;  lgW = 4; Ab = 1179648; outb = 5373952; }
  else                  { int r = Rgt - 10752; b = r >> 6;  hw0 = r & 63;   lgW = 3; Ab = 1769472; outb = 5537792; }
  int HW = 1 << (2 * lgW);
  const u16* Bbase = Bbuf + (size_t)(Rgt - Rg0) * 2304;

  int o0 = mt * 64;
  int l = t & 63, wv = t >> 6;
  int lr = l & 15, lk = l >> 4;
  int wvr = wv >> 1, wvc = wv & 1;

  int srow = t >> 2, sc4 = t & 3;
  const u16* Asrc = A + Ab + (size_t)(o0 + srow) * 2304 + sc4 * 16;
  const u16* Bsrc = Bbase + (size_t)srow * 2304 + sc4 * 16;

  f32x4 acc[2][2];
#pragma unroll
  for (int i = 0; i < 2; ++i)
#pragma unroll
    for (int j = 0; j < 2; ++j) acc[i][j] = (f32x4){0, 0, 0, 0};

  uint4 a0A, a1A, b0A, b1A, a0B, a1B, b0B, b1B;

  G_ISSUE(A, 0); G_COMMIT(A, 0);
  G_ISSUE(B, 1);
  G_ISSUE(A, 2);
  __syncthreads();
#pragma unroll 1
  for (int k2 = 0; k2 < 18; ++k2) {
    int kt = 2 * k2;
    G_MFMA(0);
    if (kt < 35) G_COMMIT(B, 1);
    __syncthreads();
    if (kt + 3 < 36) G_ISSUE(B, kt + 3);
    G_MFMA(1);
    if (kt + 1 < 35) G_COMMIT(A, 0);
    __syncthreads();
    if (kt + 4 < 36) G_ISSUE(A, kt + 4);
  }

  float* op = out + outb + (size_t)b * 256 * HW;
#pragma unroll
  for (int ar = 0; ar < 2; ++ar)
#pragma unroll
    for (int bc = 0; bc < 2; ++bc)
#pragma unroll
      for (int j = 0; j < 4; ++j) {
        int orow = o0 + wvr * 32 + ar * 16 + lk * 4 + j;
        int col = hw0 + wvc * 32 + bc * 16 + lr;
        op[(size_t)orow * HW + col] = fmaxf(acc[ar][bc][j], 0.f);
      }
}

extern "C" void kernel_launch(void* const* d_in, const int* in_sizes, int n_in,
                              void* d_out, int out_size, void* d_ws, size_t ws_size,
                              hipStream_t stream) {
  const float* x[4];
  const float* woff[4];
  const float* wad[4];
  for (int l = 0; l < 4; ++l) {
    x[l]    = (const float*)d_in[l];
    woff[l] = (const float*)d_in[4 + 2 * l];
    wad[l]  = (const float*)d_in[5 + 2 * l];
  }
  float* out = (float*)d_out;
  char* ws = (char*)d_ws;
  u32*   xq   = (u32*)(ws);
  u16*   A    = (u16*)(ws + 11141120);
  float* corr = (float*)(ws + 15859712);
  float* offs = (float*)(ws + 27875840);
  float* part = (float*)(ws + 31009280);
  u16* BbufS = (u16*)(ws + 15859712);
  u16* BbufL = (u16*)(ws + 31009280);
  int big  = (ws_size >= (size_t)81144320) ? 1 : 0;
  int part_ok = (ws_size >= (size_t)(31009280 + 18800640)) ? 1 : 0;

  prep_kernel<<<11236, 256, 0, stream>>>(x[0], x[1], x[2], x[3],
                                         wad[0], wad[1], wad[2], wad[3], xq, A, offs, out);
  corr_mfma_kernel<<<2170, 256, 0, stream>>>(xq, corr);
  offset_kernel<<<1032, 256, 0, stream>>>(corr, woff[0], woff[1], woff[2], woff[3],
                                          offs, part, part_ok);
  if (part_ok)
    reduce_kernel<<<765, 256, 0, stream>>>(part, offs);

  if (big) {
    sample_kernel<<<6120, 256, 0, stream>>>(xq, offs, BbufL, 0, 10880);
    gemm2_kernel<<<680, 256, 0, stream>>>(A, BbufL, 0, out);
  } else {
    for (int ph = 0; ph < 5; ++ph) {
      int Rg0 = ph * 2560;
      int nrows = (ph < 4) ? 2560 : 640;
      int sgrid = (nrows * 144 + 255) / 256;
      int ggrid = (nrows / 64) * 4;
      sample_kernel<<<sgrid, 256, 0, stream>>>(xq, offs, BbufS, Rg0, nrows);
      gemm2_kernel<<<ggrid, 256, 0, stream>>>(A, BbufS, Rg0, out);
    }
  }
}